// Round 1
// baseline (924.405 us; speedup 1.0000x reference)
//
#include <hip/hip_runtime.h>

// Problem constants
#define NROWS 8192   // 8*1024 flattened input vectors
#define NCODE 8192   // codebook entries
#define DIM   512

// vq_main tiling
#define BM   128
#define BN   128
#define BD   32
#define BMP  132     // padded LDS stride (132*4B = 16B-aligned rows)
#define KSPLIT 16
#define SLICE (NCODE / KSPLIT)   // 512 codewords per k-slice

// d_out layout (floats), concatenated in reference return order:
//   [0, 4194304)            quantized_st  (8,1024,512)
//   [4194304]               loss
//   [4194305, 4202497)      encoding_indices (8,1024) as float
//   [4202497, 4210689)      min_distances (8,1024)
//   [4210689]               loss_commit
#define OUT_Q      0
#define OUT_LOSS   4194304
#define OUT_IDX    4194305
#define OUT_MIND   4202497
#define OUT_COMMIT 4210689

// ws layout (floats)
#define WS_ENORM  0                  // 8192
#define WS_XNORM  8192               // 8192
#define WS_PMIN   16384              // 8192*16
#define WS_PIDX   147456             // 8192*16 (ints)
#define WS_FIDX   278528             // 8192 (ints)
#define WS_LPART  286720             // 2048

// ---------------------------------------------------------------------------
// Kernel 1: row sum-of-squares for codebook (gid<8192) and inputs (gid>=8192)
__global__ __launch_bounds__(256) void norms_kernel(const float* __restrict__ x,
                                                    const float* __restrict__ cb,
                                                    float* __restrict__ ws) {
    int gid  = blockIdx.x * 4 + (threadIdx.x >> 6);
    int lane = threadIdx.x & 63;
    const float* src;
    float* dst;
    if (gid < NCODE) { src = cb + (size_t)gid * DIM; dst = ws + WS_ENORM + gid; }
    else             { src = x + (size_t)(gid - NCODE) * DIM; dst = ws + WS_XNORM + (gid - NCODE); }
    const float4* s4 = (const float4*)src;
    float4 a = s4[lane];
    float4 b = s4[lane + 64];
    float s = a.x*a.x + a.y*a.y + a.z*a.z + a.w*a.w
            + b.x*b.x + b.y*b.y + b.z*b.z + b.w*b.w;
    #pragma unroll
    for (int o = 32; o > 0; o >>= 1) s += __shfl_down(s, o);
    if (lane == 0) *dst = s;
}

// ---------------------------------------------------------------------------
// Kernel 2: tiled distance GEMM + fused per-row argmin over a K-slice.
// grid (64, 16), block 256. Each block: 128 rows x 512-codeword slice.
__global__ __launch_bounds__(256) void vq_main_kernel(const float* __restrict__ x,
                                                      const float* __restrict__ cb,
                                                      const float* __restrict__ wsn,
                                                      float* __restrict__ pmin,
                                                      int* __restrict__ pidx) {
    __shared__ float xs[BD][BMP];   // transposed: xs[d][row]
    __shared__ float es[BD][BMP];   // transposed: es[d][col]

    const int tid = threadIdx.x;
    const int tx = tid & 15;        // 0..15  -> 8 cols each
    const int ty = tid >> 4;        // 0..15  -> 8 rows each
    const int rm  = blockIdx.x * BM;          // row base
    const int cb0 = blockIdx.y * SLICE;       // codeword slice base

    float bestd[8];
    int   besti[8];
    #pragma unroll
    for (int i = 0; i < 8; ++i) { bestd[i] = 3.4e38f; besti[i] = 0; }

    // preload x-row norms for this thread's 8 rows
    float xn[8];
    #pragma unroll
    for (int i = 0; i < 8; ++i) xn[i] = wsn[WS_XNORM + rm + ty * 8 + i];

    for (int ct = 0; ct < SLICE / BN; ++ct) {     // 4 col-tiles
        const int cn = cb0 + ct * BN;
        float acc[8][8];
        #pragma unroll
        for (int i = 0; i < 8; ++i)
            #pragma unroll
            for (int j = 0; j < 8; ++j) acc[i][j] = 0.0f;

        for (int dk = 0; dk < DIM / BD; ++dk) {   // 16 depth chunks
            const int db = dk * BD;
            // stage: 1024 float4 per matrix, 4 per thread, transposed into LDS
            #pragma unroll
            for (int u = 0; u < 4; ++u) {
                int q  = tid + u * 256;
                int r  = q >> 3;            // 0..127
                int d0 = (q & 7) << 2;      // 0,4,...,28
                float4 v = *(const float4*)(x  + (size_t)(rm + r) * DIM + db + d0);
                xs[d0 + 0][r] = v.x; xs[d0 + 1][r] = v.y;
                xs[d0 + 2][r] = v.z; xs[d0 + 3][r] = v.w;
                float4 w = *(const float4*)(cb + (size_t)(cn + r) * DIM + db + d0);
                es[d0 + 0][r] = w.x; es[d0 + 1][r] = w.y;
                es[d0 + 2][r] = w.z; es[d0 + 3][r] = w.w;
            }
            __syncthreads();

            #pragma unroll 8
            for (int d = 0; d < BD; ++d) {
                float a[8], b[8];
                *(float4*)&a[0] = *(const float4*)&xs[d][ty * 8];
                *(float4*)&a[4] = *(const float4*)&xs[d][ty * 8 + 4];
                *(float4*)&b[0] = *(const float4*)&es[d][tx * 8];
                *(float4*)&b[4] = *(const float4*)&es[d][tx * 8 + 4];
                #pragma unroll
                for (int i = 0; i < 8; ++i)
                    #pragma unroll
                    for (int j = 0; j < 8; ++j)
                        acc[i][j] += a[i] * b[j];
            }
            __syncthreads();
        }

        // distances + running argmin (cols ascending within thread)
        #pragma unroll
        for (int i = 0; i < 8; ++i) {
            #pragma unroll
            for (int j = 0; j < 8; ++j) {
                int c = cn + tx * 8 + j;
                float dist = xn[i] + wsn[WS_ENORM + c] - 2.0f * acc[i][j];
                if (dist < bestd[i]) { bestd[i] = dist; besti[i] = c; }
            }
        }
    }

    // cross-thread (over tx) argmin reduction; reuse xs/es LDS space
    float* rd = &xs[0][0];        // 128*16 floats
    int*   ri = (int*)&es[0][0];  // 128*16 ints
    #pragma unroll
    for (int i = 0; i < 8; ++i) {
        rd[(ty * 8 + i) * 16 + tx] = bestd[i];
        ri[(ty * 8 + i) * 16 + tx] = besti[i];
    }
    __syncthreads();
    if (tid < BM) {
        float bd = rd[tid * 16];
        int   bi = ri[tid * 16];
        #pragma unroll
        for (int t = 1; t < 16; ++t) {
            float d = rd[tid * 16 + t];
            int   ii = ri[tid * 16 + t];
            if (d < bd || (d == bd && ii < bi)) { bd = d; bi = ii; }
        }
        pmin[(size_t)(rm + tid) * KSPLIT + blockIdx.y] = bd;
        pidx[(size_t)(rm + tid) * KSPLIT + blockIdx.y] = bi;
    }
}

// ---------------------------------------------------------------------------
// Kernel 3: combine K-slice partials -> final idx (float + int) and min dist
__global__ __launch_bounds__(256) void combine_kernel(const float* __restrict__ pmin,
                                                      const int* __restrict__ pidx,
                                                      float* __restrict__ out_idx,
                                                      float* __restrict__ out_mind,
                                                      int* __restrict__ fidx) {
    int r = blockIdx.x * 256 + threadIdx.x;
    float bd = pmin[(size_t)r * KSPLIT];
    int   bi = pidx[(size_t)r * KSPLIT];
    #pragma unroll
    for (int s = 1; s < KSPLIT; ++s) {
        float d = pmin[(size_t)r * KSPLIT + s];
        int  ii = pidx[(size_t)r * KSPLIT + s];
        if (d < bd || (d == bd && ii < bi)) { bd = d; bi = ii; }
    }
    out_idx[r]  = (float)bi;
    out_mind[r] = bd;
    fidx[r]     = bi;
}

// ---------------------------------------------------------------------------
// Kernel 4: gather codebook rows -> quantized output; per-block commit partial
__global__ __launch_bounds__(256) void gather_kernel(const float* __restrict__ x,
                                                     const float* __restrict__ cb,
                                                     const int* __restrict__ fidx,
                                                     float* __restrict__ qout,
                                                     float* __restrict__ lpart) {
    __shared__ float sred[4];
    int row  = blockIdx.x * 4 + (threadIdx.x >> 6);
    int lane = threadIdx.x & 63;
    int idx  = fidx[row];
    const float4* e4 = (const float4*)(cb + (size_t)idx * DIM);
    const float4* x4 = (const float4*)(x + (size_t)row * DIM);
    float4* q4 = (float4*)(qout + (size_t)row * DIM);
    float s = 0.0f;
    #pragma unroll
    for (int u = 0; u < 2; ++u) {
        float4 e  = e4[lane + u * 64];
        float4 xv = x4[lane + u * 64];
        q4[lane + u * 64] = e;
        float dx = xv.x - e.x, dy = xv.y - e.y, dz = xv.z - e.z, dw = xv.w - e.w;
        s += dx * dx + dy * dy + dz * dz + dw * dw;
    }
    #pragma unroll
    for (int o = 32; o > 0; o >>= 1) s += __shfl_down(s, o);
    if (lane == 0) sred[threadIdx.x >> 6] = s;
    __syncthreads();
    if (threadIdx.x == 0) lpart[blockIdx.x] = sred[0] + sred[1] + sred[2] + sred[3];
}

// ---------------------------------------------------------------------------
// Kernel 5: final loss reduction. loss_vq == loss_commit in value =>
// loss = commit*0.25 + vq = 1.25 * commit
__global__ __launch_bounds__(256) void loss_kernel(const float* __restrict__ lpart,
                                                   float* __restrict__ out_loss,
                                                   float* __restrict__ out_commit) {
    __shared__ float sm[256];
    float s = 0.0f;
    for (int i = threadIdx.x; i < 2048; i += 256) s += lpart[i];
    sm[threadIdx.x] = s;
    __syncthreads();
    #pragma unroll
    for (int o = 128; o > 0; o >>= 1) {
        if (threadIdx.x < o) sm[threadIdx.x] += sm[threadIdx.x + o];
        __syncthreads();
    }
    if (threadIdx.x == 0) {
        *out_commit = sm[0];
        *out_loss   = 1.25f * sm[0];
    }
}

// ---------------------------------------------------------------------------
extern "C" void kernel_launch(void* const* d_in, const int* in_sizes, int n_in,
                              void* d_out, int out_size, void* d_ws, size_t ws_size,
                              hipStream_t stream) {
    const float* x  = (const float*)d_in[0];  // inputs (8,1024,512)
    const float* cb = (const float*)d_in[1];  // codebook (8192,512)
    float* out = (float*)d_out;
    float* ws  = (float*)d_ws;

    float* pmin  = ws + WS_PMIN;
    int*   pidx  = (int*)(ws + WS_PIDX);
    int*   fidx  = (int*)(ws + WS_FIDX);
    float* lpart = ws + WS_LPART;

    norms_kernel<<<4096, 256, 0, stream>>>(x, cb, ws);
    vq_main_kernel<<<dim3(NROWS / BM, KSPLIT), 256, 0, stream>>>(x, cb, ws, pmin, pidx);
    combine_kernel<<<NROWS / 256, 256, 0, stream>>>(pmin, pidx,
                                                    out + OUT_IDX, out + OUT_MIND, fidx);
    gather_kernel<<<NROWS / 4, 256, 0, stream>>>(x, cb, fidx, out + OUT_Q, lpart);
    loss_kernel<<<1, 256, 0, stream>>>(lpart, out + OUT_LOSS, out + OUT_COMMIT);
}

// Round 2
// 293.751 us; speedup vs baseline: 3.1469x; 3.1469x over previous
//
#include <hip/hip_runtime.h>

typedef __attribute__((ext_vector_type(8))) short short8;   // 8 bf16 (4 VGPRs)
typedef __attribute__((ext_vector_type(4))) float f32x4;    // MFMA acc
typedef unsigned short ushort_t;
typedef unsigned int uint32;

#define NROWS 8192
#define NCODE 8192
#define DIM   512

// ---------------- d_out layout (floats) ----------------
#define OUT_Q      0
#define OUT_LOSS   4194304
#define OUT_IDX    4194305
#define OUT_MIND   4202497
#define OUT_COMMIT 4210689

// ---------------- fast-path ws layout (floats) ----------------
#define WS_ENORM  0           // 8192
#define WS_PMIN   8192        // 8192*8
#define WS_PIDX   73728       // 8192*8 ints
#define WS_FIDX   139264      // 8192 ints
#define WS_LPART  147456      // 2048
#define WS_BHI    150528      // 8192*512 bf16 = 2097152 floats
#define WS_BLO    2247680     // same
#define WS_NEED_BYTES 17379328ull

// fallback ws layout (round-1)
#define FB_ENORM  0
#define FB_XNORM  8192
#define FB_PMIN   16384
#define FB_PIDX   147456
#define FB_FIDX   278528
#define FB_LPART  286720

// ===========================================================================
// helpers
__device__ inline uint32 bf16_rne(float f) {
    uint32 u = __float_as_uint(f);
    return (u + 0x7FFFu + ((u >> 16) & 1u)) >> 16;
}

__device__ inline void gload16(const ushort_t* g, ushort_t* l) {
    __builtin_amdgcn_global_load_lds(
        (const __attribute__((address_space(1))) void*)g,
        (__attribute__((address_space(3))) void*)l, 16, 0, 0);
}

// ===========================================================================
// FAST PATH
// ===========================================================================
// Convert inputs x -> swizzled bf16 hi/lo tiles (tile = [128 rows][32 k] row-major).
// tile id = rb*16 + kb; element off = tile*4096 + r*32 + kw.
__global__ __launch_bounds__(256) void conv_x_kernel(const float* __restrict__ x,
                                                     ushort_t* __restrict__ ahi,
                                                     ushort_t* __restrict__ alo) {
    int gid  = blockIdx.x * 256 + threadIdx.x;   // 524288 threads
    int row  = gid >> 6;
    int lane = gid & 63;
    int k0   = lane * 8;
    const float* src = x + (size_t)row * DIM + k0;
    float v[8];
    *(float4*)&v[0] = *(const float4*)src;
    *(float4*)&v[4] = *(const float4*)(src + 4);
    uint32 h[8], l[8];
    #pragma unroll
    for (int i = 0; i < 8; ++i) {
        h[i] = bf16_rne(v[i]);
        float hf = __uint_as_float(h[i] << 16);
        l[i] = bf16_rne(v[i] - hf);
    }
    int rb = row >> 7, r = row & 127;
    int kb = k0 >> 5, kw = k0 & 31;
    size_t off = ((size_t)(rb * 16 + kb)) * 4096 + r * 32 + kw;
    uint4 ph, pl;
    ph.x = h[0] | (h[1] << 16); ph.y = h[2] | (h[3] << 16);
    ph.z = h[4] | (h[5] << 16); ph.w = h[6] | (h[7] << 16);
    pl.x = l[0] | (l[1] << 16); pl.y = l[2] | (l[3] << 16);
    pl.z = l[4] | (l[5] << 16); pl.w = l[6] | (l[7] << 16);
    *(uint4*)(ahi + off) = ph;
    *(uint4*)(alo + off) = pl;
}

// Same for codebook, plus fused row-norm (fp32).
__global__ __launch_bounds__(256) void conv_cb_kernel(const float* __restrict__ cb,
                                                      ushort_t* __restrict__ bhi,
                                                      ushort_t* __restrict__ blo,
                                                      float* __restrict__ enorm) {
    int gid  = blockIdx.x * 256 + threadIdx.x;
    int row  = gid >> 6;
    int lane = gid & 63;
    int k0   = lane * 8;
    const float* src = cb + (size_t)row * DIM + k0;
    float v[8];
    *(float4*)&v[0] = *(const float4*)src;
    *(float4*)&v[4] = *(const float4*)(src + 4);
    float s = 0.0f;
    uint32 h[8], l[8];
    #pragma unroll
    for (int i = 0; i < 8; ++i) {
        s += v[i] * v[i];
        h[i] = bf16_rne(v[i]);
        float hf = __uint_as_float(h[i] << 16);
        l[i] = bf16_rne(v[i] - hf);
    }
    int rb = row >> 7, r = row & 127;
    int kb = k0 >> 5, kw = k0 & 31;
    size_t off = ((size_t)(rb * 16 + kb)) * 4096 + r * 32 + kw;
    uint4 ph, pl;
    ph.x = h[0] | (h[1] << 16); ph.y = h[2] | (h[3] << 16);
    ph.z = h[4] | (h[5] << 16); ph.w = h[6] | (h[7] << 16);
    pl.x = l[0] | (l[1] << 16); pl.y = l[2] | (l[3] << 16);
    pl.z = l[4] | (l[5] << 16); pl.w = l[6] | (l[7] << 16);
    *(uint4*)(bhi + off) = ph;
    *(uint4*)(blo + off) = pl;
    #pragma unroll
    for (int o = 32; o > 0; o >>= 1) s += __shfl_down(s, o);
    if (lane == 0) enorm[row] = s;
}

// MFMA distance-GEMM + fused per-row argmin.
// grid 512: bx = id>>3 (row block), by = id&7 (col slice, XCD-aligned).
// block = 4 waves, wave tile 64x64; block tile 128 rows x 128 cols per ct.
__global__ __launch_bounds__(256, 2) void vq_mfma_kernel(
        const ushort_t* __restrict__ ahi, const ushort_t* __restrict__ alo,
        const ushort_t* __restrict__ bhi, const ushort_t* __restrict__ blo,
        const float* __restrict__ enorm,
        float* __restrict__ pmin, int* __restrict__ pidx) {
    __shared__ __align__(16) ushort_t smem[16384];   // 32 KB
    ushort_t* Ah = smem;
    ushort_t* Al = smem + 4096;
    ushort_t* Bh = smem + 8192;
    ushort_t* Bl = smem + 12288;

    const int tid  = threadIdx.x;
    const int wave = tid >> 6, lane = tid & 63;
    const int quad = lane >> 4, l15 = lane & 15;
    const int bx = blockIdx.x >> 3;
    const int by = blockIdx.x & 7;
    const int wrow = (wave >> 1) * 64;
    const int wcol = (wave & 1) * 64;
    const int so = wave * 512 + lane * 8;   // ushort offset of lane's 16B in a 4KB site

    float bestd[16];
    int   besti[16];
    #pragma unroll
    for (int i = 0; i < 16; ++i) { bestd[i] = 3.4e38f; besti[i] = 0; }

    for (int ct = 0; ct < 8; ++ct) {
        const int ctile = by * 8 + ct;        // global col-tile 0..63
        f32x4 acc[4][4];
        #pragma unroll
        for (int i = 0; i < 4; ++i)
            #pragma unroll
            for (int j = 0; j < 4; ++j)
                acc[i][j] = (f32x4){0.f, 0.f, 0.f, 0.f};

        for (int kb = 0; kb < 16; ++kb) {
            const size_t at = ((size_t)(bx * 16 + kb)) * 4096;
            const size_t bt = ((size_t)(ctile * 16 + kb)) * 4096;
            gload16(ahi + at + so,        Ah + wave * 512);
            gload16(ahi + at + 2048 + so, Ah + 2048 + wave * 512);
            gload16(alo + at + so,        Al + wave * 512);
            gload16(alo + at + 2048 + so, Al + 2048 + wave * 512);
            gload16(bhi + bt + so,        Bh + wave * 512);
            gload16(bhi + bt + 2048 + so, Bh + 2048 + wave * 512);
            gload16(blo + bt + so,        Bl + wave * 512);
            gload16(blo + bt + 2048 + so, Bl + 2048 + wave * 512);
            __syncthreads();

            short8 a_h[4], a_l[4], b_h[4], b_l[4];
            #pragma unroll
            for (int ti = 0; ti < 4; ++ti) {
                int ar = wrow + ti * 16 + l15;
                a_h[ti] = *(const short8*)&Ah[ar * 32 + quad * 8];
                a_l[ti] = *(const short8*)&Al[ar * 32 + quad * 8];
            }
            #pragma unroll
            for (int tj = 0; tj < 4; ++tj) {
                int bc = wcol + tj * 16 + l15;
                b_h[tj] = *(const short8*)&Bh[bc * 32 + quad * 8];
                b_l[tj] = *(const short8*)&Bl[bc * 32 + quad * 8];
            }
            #pragma unroll
            for (int ti = 0; ti < 4; ++ti)
                #pragma unroll
                for (int tj = 0; tj < 4; ++tj) {
                    acc[ti][tj] = __builtin_amdgcn_mfma_f32_16x16x32_bf16(
                        a_h[ti], b_h[tj], acc[ti][tj], 0, 0, 0);
                    acc[ti][tj] = __builtin_amdgcn_mfma_f32_16x16x32_bf16(
                        a_h[ti], b_l[tj], acc[ti][tj], 0, 0, 0);
                    acc[ti][tj] = __builtin_amdgcn_mfma_f32_16x16x32_bf16(
                        a_l[ti], b_h[tj], acc[ti][tj], 0, 0, 0);
                }
            __syncthreads();
        }

        // epilogue: dist' = en[c] - 2*dot  (xn constant per row; drops out of argmin)
        const int colbase = by * 1024 + ct * 128 + wcol;
        float en[4];
        int   ci[4];
        #pragma unroll
        for (int tj = 0; tj < 4; ++tj) {
            ci[tj] = colbase + tj * 16 + l15;
            en[tj] = enorm[ci[tj]];
        }
        #pragma unroll
        for (int ti = 0; ti < 4; ++ti)
            #pragma unroll
            for (int tj = 0; tj < 4; ++tj)
                #pragma unroll
                for (int reg = 0; reg < 4; ++reg) {
                    float d = en[tj] - 2.0f * acc[ti][tj][reg];
                    int bi = ti * 4 + reg;
                    if (d < bestd[bi]) { bestd[bi] = d; besti[bi] = ci[tj]; }
                }
    }

    // block-level per-row reduction: 32 candidates/row (2 waves x 16 lanes)
    float* rd = (float*)smem;            // 128*32 floats = 16 KB
    int*   ri = (int*)smem + 4096;       // 128*32 ints   = 16 KB
    __syncthreads();
    #pragma unroll
    for (int ti = 0; ti < 4; ++ti)
        #pragma unroll
        for (int reg = 0; reg < 4; ++reg) {
            int rloc = wrow + ti * 16 + quad * 4 + reg;   // C/D layout row
            int slot = (wave & 1) * 16 + l15;
            rd[rloc * 32 + slot] = bestd[ti * 4 + reg];
            ri[rloc * 32 + slot] = besti[ti * 4 + reg];
        }
    __syncthreads();
    if (tid < 128) {
        float bd = rd[tid * 32];
        int   bi = ri[tid * 32];
        #pragma unroll
        for (int t = 1; t < 32; ++t) {
            float d = rd[tid * 32 + t];
            int  ii = ri[tid * 32 + t];
            if (d < bd || (d == bd && ii < bi)) { bd = d; bi = ii; }
        }
        pmin[(size_t)(bx * 128 + tid) * 8 + by] = bd;
        pidx[(size_t)(bx * 128 + tid) * 8 + by] = bi;
    }
}

__global__ __launch_bounds__(256) void combine2_kernel(const float* __restrict__ pmin,
                                                       const int* __restrict__ pidx,
                                                       float* __restrict__ out_idx,
                                                       int* __restrict__ fidx) {
    int r = blockIdx.x * 256 + threadIdx.x;
    float bd = pmin[(size_t)r * 8];
    int   bi = pidx[(size_t)r * 8];
    #pragma unroll
    for (int s = 1; s < 8; ++s) {
        float d = pmin[(size_t)r * 8 + s];
        int  ii = pidx[(size_t)r * 8 + s];
        if (d < bd || (d == bd && ii < bi)) { bd = d; bi = ii; }
    }
    out_idx[r] = (float)bi;
    fidx[r]    = bi;
}

// gather codebook rows -> quantized; exact fp32 ||x-e||^2 -> min_distances + loss partials
__global__ __launch_bounds__(256) void gather2_kernel(const float* __restrict__ x,
                                                      const float* __restrict__ cb,
                                                      const int* __restrict__ fidx,
                                                      float* __restrict__ qout,
                                                      float* __restrict__ out_mind,
                                                      float* __restrict__ lpart) {
    __shared__ float sred[4];
    int row  = blockIdx.x * 4 + (threadIdx.x >> 6);
    int lane = threadIdx.x & 63;
    int idx  = fidx[row];
    const float4* e4 = (const float4*)(cb + (size_t)idx * DIM);
    const float4* x4 = (const float4*)(x + (size_t)row * DIM);
    float4* q4 = (float4*)(qout + (size_t)row * DIM);
    float s = 0.0f;
    #pragma unroll
    for (int u = 0; u < 2; ++u) {
        float4 e  = e4[lane + u * 64];
        float4 xv = x4[lane + u * 64];
        q4[lane + u * 64] = e;
        float dx = xv.x - e.x, dy = xv.y - e.y, dz = xv.z - e.z, dw = xv.w - e.w;
        s += dx * dx + dy * dy + dz * dz + dw * dw;
    }
    #pragma unroll
    for (int o = 32; o > 0; o >>= 1) s += __shfl_down(s, o);
    if (lane == 0) { sred[threadIdx.x >> 6] = s; out_mind[row] = s; }
    __syncthreads();
    if (threadIdx.x == 0) lpart[blockIdx.x] = sred[0] + sred[1] + sred[2] + sred[3];
}

__global__ __launch_bounds__(256) void loss_kernel(const float* __restrict__ lpart,
                                                   float* __restrict__ out_loss,
                                                   float* __restrict__ out_commit) {
    __shared__ float sm[256];
    float s = 0.0f;
    for (int i = threadIdx.x; i < 2048; i += 256) s += lpart[i];
    sm[threadIdx.x] = s;
    __syncthreads();
    #pragma unroll
    for (int o = 128; o > 0; o >>= 1) {
        if (threadIdx.x < o) sm[threadIdx.x] += sm[threadIdx.x + o];
        __syncthreads();
    }
    if (threadIdx.x == 0) {
        *out_commit = sm[0];
        *out_loss   = 1.25f * sm[0];
    }
}

// ===========================================================================
// FALLBACK PATH (round-1 fp32, known-correct) — used only if ws is too small
// ===========================================================================
#define BM 128
#define BN 128
#define BD 32
#define BMP 132
#define KSPLIT 16
#define SLICE (NCODE / KSPLIT)

__global__ __launch_bounds__(256) void norms_kernel(const float* __restrict__ x,
                                                    const float* __restrict__ cb,
                                                    float* __restrict__ ws) {
    int gid  = blockIdx.x * 4 + (threadIdx.x >> 6);
    int lane = threadIdx.x & 63;
    const float* src;
    float* dst;
    if (gid < NCODE) { src = cb + (size_t)gid * DIM; dst = ws + FB_ENORM + gid; }
    else             { src = x + (size_t)(gid - NCODE) * DIM; dst = ws + FB_XNORM + (gid - NCODE); }
    const float4* s4 = (const float4*)src;
    float4 a = s4[lane];
    float4 b = s4[lane + 64];
    float s = a.x*a.x + a.y*a.y + a.z*a.z + a.w*a.w
            + b.x*b.x + b.y*b.y + b.z*b.z + b.w*b.w;
    #pragma unroll
    for (int o = 32; o > 0; o >>= 1) s += __shfl_down(s, o);
    if (lane == 0) *dst = s;
}

__global__ __launch_bounds__(256) void vq_main_kernel(const float* __restrict__ x,
                                                      const float* __restrict__ cb,
                                                      const float* __restrict__ wsn,
                                                      float* __restrict__ pmin,
                                                      int* __restrict__ pidx) {
    __shared__ float xs[BD][BMP];
    __shared__ float es[BD][BMP];
    const int tid = threadIdx.x;
    const int tx = tid & 15;
    const int ty = tid >> 4;
    const int rm  = blockIdx.x * BM;
    const int cb0 = blockIdx.y * SLICE;
    float bestd[8];
    int   besti[8];
    #pragma unroll
    for (int i = 0; i < 8; ++i) { bestd[i] = 3.4e38f; besti[i] = 0; }
    float xn[8];
    #pragma unroll
    for (int i = 0; i < 8; ++i) xn[i] = wsn[FB_XNORM + rm + ty * 8 + i];
    for (int ct = 0; ct < SLICE / BN; ++ct) {
        const int cn = cb0 + ct * BN;
        float acc[8][8];
        #pragma unroll
        for (int i = 0; i < 8; ++i)
            #pragma unroll
            for (int j = 0; j < 8; ++j) acc[i][j] = 0.0f;
        for (int dk = 0; dk < DIM / BD; ++dk) {
            const int db = dk * BD;
            #pragma unroll
            for (int u = 0; u < 4; ++u) {
                int q  = tid + u * 256;
                int r  = q >> 3;
                int d0 = (q & 7) << 2;
                float4 v = *(const float4*)(x  + (size_t)(rm + r) * DIM + db + d0);
                xs[d0 + 0][r] = v.x; xs[d0 + 1][r] = v.y;
                xs[d0 + 2][r] = v.z; xs[d0 + 3][r] = v.w;
                float4 w = *(const float4*)(cb + (size_t)(cn + r) * DIM + db + d0);
                es[d0 + 0][r] = w.x; es[d0 + 1][r] = w.y;
                es[d0 + 2][r] = w.z; es[d0 + 3][r] = w.w;
            }
            __syncthreads();
            #pragma unroll 8
            for (int d = 0; d < BD; ++d) {
                float a[8], b[8];
                *(float4*)&a[0] = *(const float4*)&xs[d][ty * 8];
                *(float4*)&a[4] = *(const float4*)&xs[d][ty * 8 + 4];
                *(float4*)&b[0] = *(const float4*)&es[d][tx * 8];
                *(float4*)&b[4] = *(const float4*)&es[d][tx * 8 + 4];
                #pragma unroll
                for (int i = 0; i < 8; ++i)
                    #pragma unroll
                    for (int j = 0; j < 8; ++j)
                        acc[i][j] += a[i] * b[j];
            }
            __syncthreads();
        }
        #pragma unroll
        for (int i = 0; i < 8; ++i) {
            #pragma unroll
            for (int j = 0; j < 8; ++j) {
                int c = cn + tx * 8 + j;
                float dist = xn[i] + wsn[FB_ENORM + c] - 2.0f * acc[i][j];
                if (dist < bestd[i]) { bestd[i] = dist; besti[i] = c; }
            }
        }
    }
    float* rd = &xs[0][0];
    int*   ri = (int*)&es[0][0];
    #pragma unroll
    for (int i = 0; i < 8; ++i) {
        rd[(ty * 8 + i) * 16 + tx] = bestd[i];
        ri[(ty * 8 + i) * 16 + tx] = besti[i];
    }
    __syncthreads();
    if (tid < BM) {
        float bd = rd[tid * 16];
        int   bi = ri[tid * 16];
        #pragma unroll
        for (int t = 1; t < 16; ++t) {
            float d = rd[tid * 16 + t];
            int   ii = ri[tid * 16 + t];
            if (d < bd || (d == bd && ii < bi)) { bd = d; bi = ii; }
        }
        pmin[(size_t)(rm + tid) * KSPLIT + blockIdx.y] = bd;
        pidx[(size_t)(rm + tid) * KSPLIT + blockIdx.y] = bi;
    }
}

__global__ __launch_bounds__(256) void combine_kernel(const float* __restrict__ pmin,
                                                      const int* __restrict__ pidx,
                                                      float* __restrict__ out_idx,
                                                      float* __restrict__ out_mind,
                                                      int* __restrict__ fidx) {
    int r = blockIdx.x * 256 + threadIdx.x;
    float bd = pmin[(size_t)r * KSPLIT];
    int   bi = pidx[(size_t)r * KSPLIT];
    #pragma unroll
    for (int s = 1; s < KSPLIT; ++s) {
        float d = pmin[(size_t)r * KSPLIT + s];
        int  ii = pidx[(size_t)r * KSPLIT + s];
        if (d < bd || (d == bd && ii < bi)) { bd = d; bi = ii; }
    }
    out_idx[r]  = (float)bi;
    out_mind[r] = bd;
    fidx[r]     = bi;
}

// ===========================================================================
extern "C" void kernel_launch(void* const* d_in, const int* in_sizes, int n_in,
                              void* d_out, int out_size, void* d_ws, size_t ws_size,
                              hipStream_t stream) {
    const float* x  = (const float*)d_in[0];
    const float* cb = (const float*)d_in[1];
    float* out = (float*)d_out;
    float* ws  = (float*)d_ws;

    if (ws_size >= WS_NEED_BYTES) {
        // fast path: bf16-split MFMA
        ushort_t* ahi = (ushort_t*)d_out;               // quantized region, phase 1
        ushort_t* alo = (ushort_t*)d_out + 4194304;
        ushort_t* bhi = (ushort_t*)(ws + WS_BHI);
        ushort_t* blo = (ushort_t*)(ws + WS_BLO);
        float* enorm = ws + WS_ENORM;
        float* pmin  = ws + WS_PMIN;
        int*   pidx  = (int*)(ws + WS_PIDX);
        int*   fidx  = (int*)(ws + WS_FIDX);
        float* lpart = ws + WS_LPART;

        conv_x_kernel <<<2048, 256, 0, stream>>>(x, ahi, alo);
        conv_cb_kernel<<<2048, 256, 0, stream>>>(cb, bhi, blo, enorm);
        vq_mfma_kernel<<<512, 256, 0, stream>>>(ahi, alo, bhi, blo, enorm, pmin, pidx);
        combine2_kernel<<<NROWS / 256, 256, 0, stream>>>(pmin, pidx, out + OUT_IDX, fidx);
        gather2_kernel<<<NROWS / 4, 256, 0, stream>>>(x, cb, fidx, out + OUT_Q,
                                                      out + OUT_MIND, lpart);
        loss_kernel<<<1, 256, 0, stream>>>(lpart, out + OUT_LOSS, out + OUT_COMMIT);
    } else {
        // fallback: fp32 path (round-1)
        float* pmin  = ws + FB_PMIN;
        int*   pidx  = (int*)(ws + FB_PIDX);
        int*   fidx  = (int*)(ws + FB_FIDX);
        float* lpart = ws + FB_LPART;

        norms_kernel<<<4096, 256, 0, stream>>>(x, cb, ws);
        vq_main_kernel<<<dim3(NROWS / BM, KSPLIT), 256, 0, stream>>>(x, cb, ws, pmin, pidx);
        combine_kernel<<<NROWS / 256, 256, 0, stream>>>(pmin, pidx, out + OUT_IDX,
                                                        out + OUT_MIND, fidx);
        gather2_kernel<<<NROWS / 4, 256, 0, stream>>>(x, cb, fidx, out + OUT_Q,
                                                      out + OUT_MIND, lpart);
        loss_kernel<<<1, 256, 0, stream>>>(lpart, out + OUT_LOSS, out + OUT_COMMIT);
    }
}

// Round 3
// 278.420 us; speedup vs baseline: 3.3202x; 1.0551x over previous
//
#include <hip/hip_runtime.h>

typedef __attribute__((ext_vector_type(8)))  short short8;   // 8 bf16 (4 VGPRs)
typedef __attribute__((ext_vector_type(16))) float f32x16;   // 32x32 MFMA acc
typedef unsigned short ushort_t;
typedef unsigned int uint32;

#define NROWS 8192
#define NCODE 8192
#define DIM   512

// ---------------- d_out layout (floats) ----------------
#define OUT_Q      0
#define OUT_LOSS   4194304
#define OUT_IDX    4194305
#define OUT_MIND   4202497
#define OUT_COMMIT 4210689

// ---------------- ws layout (floats) ----------------
#define WS_ENORM  0           // 8192
#define WS_PMIN   8192        // 8192*8
#define WS_PIDX   73728       // 8192*8 ints
#define WS_LPART  147456      // 2048
#define WS_BHI    150528      // 8192*512 bf16
#define WS_BLO    2247680

// ===========================================================================
__device__ inline uint32 bf16_rne(float f) {
    uint32 u = __float_as_uint(f);
    return (u + 0x7FFFu + ((u >> 16) & 1u)) >> 16;
}

__device__ inline void gload16(const ushort_t* g, ushort_t* l) {
    __builtin_amdgcn_global_load_lds(
        (const __attribute__((address_space(1))) void*)g,
        (__attribute__((address_space(3))) void*)l, 16, 0, 0);
}

// ===========================================================================
// Kernel 1: fused conversion of x and codebook into fragment-ordered bf16
// hi/lo tiles. Tile = 128 rows x 32 k, 8 KB, stored as 8 chunks of 1 KB:
//   chunk c = (r32)*2 + k16 ; within chunk lane L holds 8 bf16:
//   row = r32*32 + (L&31), k = k16*16 + (L>>5)*8 + j
// This IS the mfma_32x32x16 A/B fragment order -> conflict-free ds_read_b128
// and identity global_load_lds staging.
__global__ __launch_bounds__(256) void conv_kernel(const float* __restrict__ x,
                                                   const float* __restrict__ cb,
                                                   ushort_t* __restrict__ ahi,
                                                   ushort_t* __restrict__ alo,
                                                   ushort_t* __restrict__ bhi,
                                                   ushort_t* __restrict__ blo,
                                                   float* __restrict__ enorm) {
    int gid  = blockIdx.x * 256 + threadIdx.x;   // 0..1048575
    bool isA = gid < 524288;
    int g    = isA ? gid : gid - 524288;
    int row  = g >> 6;
    int lane = g & 63;
    int k0   = lane * 8;
    const float* src = (isA ? x : cb) + (size_t)row * DIM + k0;
    float v[8];
    *(float4*)&v[0] = *(const float4*)src;
    *(float4*)&v[4] = *(const float4*)(src + 4);
    float s = 0.0f;
    uint32 h[8], l[8];
    #pragma unroll
    for (int i = 0; i < 8; ++i) {
        s += v[i] * v[i];
        h[i] = bf16_rne(v[i]);
        float hf = __uint_as_float(h[i] << 16);
        l[i] = bf16_rne(v[i] - hf);
    }
    // fragment-ordered offset
    int tile = (row >> 7) * 16 + (k0 >> 5);
    int rp = row & 127, kp = k0 & 31;
    int c  = (rp >> 5) * 2 + (kp >> 4);
    int L  = (rp & 31) + (((kp >> 3) & 1) << 5);
    size_t off = (size_t)tile * 4096 + c * 512 + L * 8;   // ushort units
    uint4 ph, pl;
    ph.x = h[0] | (h[1] << 16); ph.y = h[2] | (h[3] << 16);
    ph.z = h[4] | (h[5] << 16); ph.w = h[6] | (h[7] << 16);
    pl.x = l[0] | (l[1] << 16); pl.y = l[2] | (l[3] << 16);
    pl.z = l[4] | (l[5] << 16); pl.w = l[6] | (l[7] << 16);
    if (isA) {
        *(uint4*)(ahi + off) = ph;
        *(uint4*)(alo + off) = pl;
    } else {
        *(uint4*)(bhi + off) = ph;
        *(uint4*)(blo + off) = pl;
        #pragma unroll
        for (int o = 32; o > 0; o >>= 1) s += __shfl_down(s, o);
        if (lane == 0) enorm[row] = s;
    }
}

// ===========================================================================
// Kernel 2: MFMA distance-GEMM + fused per-row argmin.
// grid 512, block 256 (4 waves, wave tile 64x64 = 2x2 of 32x32x16).
// XCD swizzle: XCD j = q%8 hosts bx in [8j,8j+8) -> 2 MB A stays L2-resident.
__global__ __launch_bounds__(256, 2) void vq_mfma_kernel(
        const ushort_t* __restrict__ ahi, const ushort_t* __restrict__ alo,
        const ushort_t* __restrict__ bhi, const ushort_t* __restrict__ blo,
        const float* __restrict__ enorm,
        float* __restrict__ pmin, int* __restrict__ pidx) {
    __shared__ __align__(16) ushort_t smem[32768];   // 64 KB = 2 x 32 KB buffers

    const int tid  = threadIdx.x;
    const int wave = tid >> 6, lane = tid & 63;
    const int l31  = lane & 31, half = lane >> 5;
    const int q  = blockIdx.x;
    const int bx = (q & 7) * 8 + (q >> 6);    // 0..63, bx&... XCD = q%8
    const int by = (q >> 3) & 7;              // 0..7 col slice (1024 cols)
    const int wrow = (wave >> 1) * 64;
    const int wcol = (wave & 1) * 64;
    const int so = wave * 512 + lane * 8;     // ushort offset inside 4 KB chunk

    f32x16 acc[2][2];
    #pragma unroll
    for (int i = 0; i < 2; ++i)
        #pragma unroll
        for (int j = 0; j < 2; ++j)
            #pragma unroll
            for (int r = 0; r < 16; ++r) acc[i][j][r] = 0.0f;

    float bestd[32];
    int   besti[32];
    #pragma unroll
    for (int i = 0; i < 32; ++i) { bestd[i] = 3.4e38f; besti[i] = 0x7FFFFFFF; }

    // ---- stage tile n into buffer n&1 ----
    auto stage = [&](int n) {
        const int kb = n & 15;
        const int ctile = by * 8 + (n >> 4);
        const size_t at = (size_t)(bx * 16 + kb) * 4096;
        const size_t bt = (size_t)(ctile * 16 + kb) * 4096;
        ushort_t* S = smem + (n & 1) * 16384;
        gload16(ahi + at + so,        S + so);
        gload16(ahi + at + 2048 + so, S + 2048 + so);
        gload16(alo + at + so,        S + 4096 + so);
        gload16(alo + at + 2048 + so, S + 6144 + so);
        gload16(bhi + bt + so,        S + 8192 + so);
        gload16(bhi + bt + 2048 + so, S + 10240 + so);
        gload16(blo + bt + so,        S + 12288 + so);
        gload16(blo + bt + 2048 + so, S + 14336 + so);
    };

    stage(0);

    for (int n = 0; n < 128; ++n) {
        __syncthreads();                // drains stage(n); frees buffer (n+1)&1
        if (n + 1 < 128) stage(n + 1);  // async into other buffer, no wait

        ushort_t* S = smem + (n & 1) * 16384;
        #pragma unroll
        for (int k16 = 0; k16 < 2; ++k16) {
            short8 ah[2], al[2], bh[2], bl[2];
            #pragma unroll
            for (int ti = 0; ti < 2; ++ti) {
                int ca = ((wrow >> 5) + ti) * 2 + k16;
                ah[ti] = *(const short8*)&S[ca * 512 + lane * 8];
                al[ti] = *(const short8*)&S[4096 + ca * 512 + lane * 8];
            }
            #pragma unroll
            for (int tj = 0; tj < 2; ++tj) {
                int cb_ = ((wcol >> 5) + tj) * 2 + k16;
                bh[tj] = *(const short8*)&S[8192 + cb_ * 512 + lane * 8];
                bl[tj] = *(const short8*)&S[12288 + cb_ * 512 + lane * 8];
            }
            #pragma unroll
            for (int ti = 0; ti < 2; ++ti)
                #pragma unroll
                for (int tj = 0; tj < 2; ++tj) {
                    acc[ti][tj] = __builtin_amdgcn_mfma_f32_32x32x16_bf16(
                        ah[ti], bh[tj], acc[ti][tj], 0, 0, 0);
                    acc[ti][tj] = __builtin_amdgcn_mfma_f32_32x32x16_bf16(
                        ah[ti], bl[tj], acc[ti][tj], 0, 0, 0);
                    acc[ti][tj] = __builtin_amdgcn_mfma_f32_32x32x16_bf16(
                        al[ti], bh[tj], acc[ti][tj], 0, 0, 0);
                }
        }

        if ((n & 15) == 15) {
            // epilogue for col tile ct: dist' = ||e||^2 - 2*dot (xn drops out)
            const int ct = n >> 4;
            const int colbase = by * 1024 + ct * 128 + wcol;
            #pragma unroll
            for (int tj = 0; tj < 2; ++tj) {
                const int ci = colbase + tj * 32 + l31;
                const float en = enorm[ci];
                #pragma unroll
                for (int ti = 0; ti < 2; ++ti)
                    #pragma unroll
                    for (int reg = 0; reg < 16; ++reg) {
                        float d = en - 2.0f * acc[ti][tj][reg];
                        int s = ti * 16 + reg;
                        if (d < bestd[s]) { bestd[s] = d; besti[s] = ci; }
                    }
            }
            #pragma unroll
            for (int i = 0; i < 2; ++i)
                #pragma unroll
                for (int j = 0; j < 2; ++j)
                    #pragma unroll
                    for (int r = 0; r < 16; ++r) acc[i][j][r] = 0.0f;
        }
    }

    // ---- block argmin reduction: 64 candidates per row ----
    // slot-major [slot][128 rows]: conflict-free reads in the scan phase
    float* rd = (float*)smem;           // 64*128 floats = 32 KB
    int*   ri = (int*)smem + 8192;      // 64*128 ints   = 32 KB
    __syncthreads();
    const int slot = (wave & 1) * 32 + l31;
    #pragma unroll
    for (int ti = 0; ti < 2; ++ti)
        #pragma unroll
        for (int reg = 0; reg < 16; ++reg) {
            int row = wrow + ti * 32 + (reg & 3) + 8 * (reg >> 2) + 4 * half;
            rd[slot * 128 + row] = bestd[ti * 16 + reg];
            ri[slot * 128 + row] = besti[ti * 16 + reg];
        }
    __syncthreads();
    if (tid < 128) {
        float bd = rd[tid];
        int   bi = ri[tid];
        #pragma unroll 8
        for (int t = 1; t < 64; ++t) {
            float d = rd[t * 128 + tid];
            int  ii = ri[t * 128 + tid];
            if (d < bd || (d == bd && ii < bi)) { bd = d; bi = ii; }
        }
        pmin[(size_t)(bx * 128 + tid) * 8 + by] = bd;
        pidx[(size_t)(bx * 128 + tid) * 8 + by] = bi;
    }
}

// ===========================================================================
// Kernel 3: combine slice partials -> idx, then gather codebook row,
// exact fp32 ||x-e||^2 -> min_distances + loss partials. One 64-lane group/row.
__global__ __launch_bounds__(256) void finish_kernel(const float* __restrict__ x,
                                                     const float* __restrict__ cb,
                                                     const float* __restrict__ pmin,
                                                     const int* __restrict__ pidx,
                                                     float* __restrict__ out_idx,
                                                     float* __restrict__ qout,
                                                     float* __restrict__ out_mind,
                                                     float* __restrict__ lpart) {
    __shared__ float sred[4];
    int row  = blockIdx.x * 4 + (threadIdx.x >> 6);
    int lane = threadIdx.x & 63;

    // per-row argmin over the 8 slice partials (lanes 0..7 active)
    float d = (lane < 8) ? pmin[(size_t)row * 8 + lane] : 3.4e38f;
    int  ii = (lane < 8) ? pidx[(size_t)row * 8 + lane] : 0x7FFFFFFF;
    #pragma unroll
    for (int o = 4; o > 0; o >>= 1) {
        float d2 = __shfl_down(d, o);
        int   i2 = __shfl_down(ii, o);
        if (d2 < d || (d2 == d && i2 < ii)) { d = d2; ii = i2; }
    }
    int idx = __shfl(ii, 0);
    if (lane == 0) out_idx[row] = (float)idx;

    const float4* e4 = (const float4*)(cb + (size_t)idx * DIM);
    const float4* x4 = (const float4*)(x + (size_t)row * DIM);
    float4* q4 = (float4*)(qout + (size_t)row * DIM);
    float s = 0.0f;
    #pragma unroll
    for (int u = 0; u < 2; ++u) {
        float4 e  = e4[lane + u * 64];
        float4 xv = x4[lane + u * 64];
        q4[lane + u * 64] = e;
        float dx = xv.x - e.x, dy = xv.y - e.y, dz = xv.z - e.z, dw = xv.w - e.w;
        s += dx * dx + dy * dy + dz * dz + dw * dw;
    }
    #pragma unroll
    for (int o = 32; o > 0; o >>= 1) s += __shfl_down(s, o);
    if (lane == 0) { sred[threadIdx.x >> 6] = s; out_mind[row] = s; }
    __syncthreads();
    if (threadIdx.x == 0) lpart[blockIdx.x] = sred[0] + sred[1] + sred[2] + sred[3];
}

// ===========================================================================
// Kernel 4: final loss. loss_vq == loss_commit numerically => loss = 1.25*commit
__global__ __launch_bounds__(256) void loss_kernel(const float* __restrict__ lpart,
                                                   float* __restrict__ out_loss,
                                                   float* __restrict__ out_commit) {
    __shared__ float sm[256];
    float s = 0.0f;
    for (int i = threadIdx.x; i < 2048; i += 256) s += lpart[i];
    sm[threadIdx.x] = s;
    __syncthreads();
    #pragma unroll
    for (int o = 128; o > 0; o >>= 1) {
        if (threadIdx.x < o) sm[threadIdx.x] += sm[threadIdx.x + o];
        __syncthreads();
    }
    if (threadIdx.x == 0) {
        *out_commit = sm[0];
        *out_loss   = 1.25f * sm[0];
    }
}

// ===========================================================================
extern "C" void kernel_launch(void* const* d_in, const int* in_sizes, int n_in,
                              void* d_out, int out_size, void* d_ws, size_t ws_size,
                              hipStream_t stream) {
    const float* x  = (const float*)d_in[0];
    const float* cb = (const float*)d_in[1];
    float* out = (float*)d_out;
    float* ws  = (float*)d_ws;

    // A hi/lo staged in the quantized-output region (rewritten by finish_kernel)
    ushort_t* ahi = (ushort_t*)d_out;
    ushort_t* alo = (ushort_t*)d_out + 4194304;
    ushort_t* bhi = (ushort_t*)(ws + WS_BHI);
    ushort_t* blo = (ushort_t*)(ws + WS_BLO);
    float* enorm = ws + WS_ENORM;
    float* pmin  = ws + WS_PMIN;
    int*   pidx  = (int*)(ws + WS_PIDX);
    float* lpart = ws + WS_LPART;

    conv_kernel<<<4096, 256, 0, stream>>>(x, cb, ahi, alo, bhi, blo, enorm);
    vq_mfma_kernel<<<512, 256, 0, stream>>>(ahi, alo, bhi, blo, enorm, pmin, pidx);
    finish_kernel<<<NROWS / 4, 256, 0, stream>>>(x, cb, pmin, pidx,
                                                 out + OUT_IDX, out + OUT_Q,
                                                 out + OUT_MIND, lpart);
    loss_kernel<<<1, 256, 0, stream>>>(lpart, out + OUT_LOSS, out + OUT_COMMIT);
}